// Round 8
// baseline (172.228 us; speedup 1.0000x reference)
//
#include <hip/hip_runtime.h>
#include <hip/hip_bf16.h>

#define T 50
#define NB 64
#define NS 512
#define START_TAG 48
#define STOP_TAG 49
#define NCH 8          // time chunks
#define CHL 64         // steps per chunk
#define PITCH 72       // LDS halfword pitch: 144B rows -> b128-aligned, 2-way banks only

typedef _Float16 f16_t;
typedef _Float16 f16x2 __attribute__((ext_vector_type(2)));
typedef _Float16 f16x8 __attribute__((ext_vector_type(8)));
typedef float    f32x4 __attribute__((ext_vector_type(4)));

static constexpr float LOG2E = 1.4426950408889634f;
static constexpr float LN2F  = 0.6931471805599453f;
static constexpr float S_E   = 6.0f;     // static log2 shift folded out of E
#define NEG_BIG (-1.0e38f)

__device__ __forceinline__ float fexp2(float x) { return __builtin_amdgcn_exp2f(x); }
__device__ __forceinline__ float flog2(float x) { return __builtin_amdgcn_logf(x); }
__device__ __forceinline__ float bcastf(float v, int src) {
    return __uint_as_float(__builtin_amdgcn_readlane(__float_as_uint(v), src));
}
__device__ __forceinline__ f16x2 bcast_h2(f16x2 v, int src) {
    unsigned u = __builtin_amdgcn_readlane(__builtin_bit_cast(unsigned, v), src);
    return __builtin_bit_cast(f16x2, u);
}
__device__ __forceinline__ f16x2 pack_h2(float a, float b) {
    return __builtin_bit_cast(f16x2, __builtin_amdgcn_cvt_pkrtz(a, b));
}

// =====================================================================
// Kernel 1: per (batch, chunk) compute P_c = prod_t (E * D_t) by 64
// sequential 16x64x64-per-wave MFMA steps. KEY: wave w's row block
// [16w,16w+16) evolves independently (A-read and store touch only its own
// rows) -> NO barrier in the K-loop. Per-wave scale smax in registers,
// reduced with 4 DPP shfl + 4 readlane (no ds_permute, no LDS round trip).
// Per-wave shift D_w stored; combine recombines the 4 block scales exactly.
// =====================================================================
__global__ __launch_bounds__(256, 1)
void crf_chunk(const float* __restrict__ feats, const int* __restrict__ mask,
               const float* __restrict__ trans, f16_t* __restrict__ wsCt,
               float* __restrict__ wsD, float* __restrict__ out) {
    const int c    = blockIdx.x;          // chunk
    const int b    = blockIdx.y;          // batch
    const int tid  = threadIdx.x;
    const int w    = tid >> 6;
    const int lane = tid & 63;
    const int l15  = lane & 15;
    const int q    = lane >> 4;

    __shared__ __align__(16) f16_t sC[2][64 * PITCH];  // C_raw, double-buffered
    __shared__ float sF[CHL][64];         // 2^(f_t*log2e) per step/col (preloaded)
    __shared__ int   sMk[CHL];            // masks (preloaded)

    if (c == 0 && b == 0 && tid == 0) out[0] = 0.f;   // replaces memset dispatch

    const int t0  = c * CHL + 1;
    const int nst = NS - t0 < CHL ? NS - t0 : CHL;

    // ---- E fragments (B-operand layout: n = 16*c2 + l15, k = 32*kb + q*8 + jj)
    f16x8 Efrag[2][4];
    #pragma unroll
    for (int kb = 0; kb < 2; kb++)
        #pragma unroll
        for (int c2 = 0; c2 < 4; c2++) {
            f16x8 v;
            #pragma unroll
            for (int jj = 0; jj < 8; jj++) {
                int kk = 32 * kb + q * 8 + jj;
                int nn = 16 * c2 + l15;
                float x = 0.f;
                if (kk < T && nn < T) x = fexp2(fmaf(trans[kk * T + nn], LOG2E, -S_E));
                v[jj] = (f16_t)x;
            }
            Efrag[kb][c2] = v;
        }

    // ---- bulk preload: feats block (exp2 once) + masks
    for (int r = w; r < CHL; r += 4) {
        int tl = t0 + r; tl = tl < NS ? tl : NS - 1;
        float fv = (lane < T && r < nst) ? feats[((size_t)b * NS + tl) * T + lane] : 0.f;
        sF[r][lane] = (lane < T && r < nst) ? fexp2(fv * LOG2E) : 0.f;
    }
    if (tid < CHL) {
        int tl = t0 + tid; tl = tl < NS ? tl : NS - 1;
        sMk[tid] = (tid < nst) ? mask[b * NS + tl] : 0;
    }

    // ---- init: C = I (64x64) in buf 0
    for (int idx = tid; idx < 64 * PITCH; idx += 256) sC[0][idx] = (f16_t)0.f;
    if (tid < 64) sC[0][tid * PITCH + tid] = (f16_t)1.f;
    __syncthreads();   // the ONLY barrier

    float D    = 0.f;
    float smax = 1.f;                     // per-wave max (identity block)
    int   cb   = 0;
    int   mk   = sMk[0];

    for (int s = 0; s < nst; s++) {
        const bool doit = (mk != 0);
        mk = (s + 1 < CHL) ? sMk[s + 1] : 0;

        if (doit) {
            // per-wave renorm shift (registers only, no LDS)
            int ebits = (int)((__float_as_uint(smax) >> 23) & 255) - 127;
            ebits = ebits > 14 ? 14 : (ebits < -14 ? -14 : ebits);
            D += (float)ebits + S_E;
            const float descale = __uint_as_float((unsigned)(127 - ebits) << 23);
            const f16_t dsc = (f16_t)descale;
            f16x8 dspl;
            #pragma unroll
            for (int z = 0; z < 8; z++) dspl[z] = dsc;

            // A fragments: one aligned b128 per kb (own rows only)
            const int abase = (16 * w + l15) * PITCH + 8 * q;
            f16x8 A0 = (*(const f16x8*)&sC[cb][abase])      * dspl;
            f16x8 A1 = (*(const f16x8*)&sC[cb][abase + 32]) * dspl;

            // 8 MFMAs: rows [16w,16w+16) x 4 col-blocks
            f32x4 acc[4];
            #pragma unroll
            for (int c2 = 0; c2 < 4; c2++) {
                acc[c2] = __builtin_amdgcn_mfma_f32_16x16x32_f16(A0, Efrag[0][c2],
                                                                 (f32x4){0.f,0.f,0.f,0.f}, 0, 0, 0);
                acc[c2] = __builtin_amdgcn_mfma_f32_16x16x32_f16(A1, Efrag[1][c2],
                                                                 acc[c2], 0, 0, 0);
            }

            // epilogue: col scale, pair-pack via DPP, half-wave b32 stores
            const int nb2 = cb ^ 1;
            float wmax = 0.f;
            #pragma unroll
            for (int c2 = 0; c2 < 4; c2++) {
                const float cs = sF[s][16 * c2 + l15];
                float vv[4];
                #pragma unroll
                for (int r = 0; r < 4; r++) vv[r] = acc[c2][r] * cs;
                wmax = fmaxf(wmax, fmaxf(fmaxf(vv[0], vv[1]), fmaxf(vv[2], vv[3])));
                #pragma unroll
                for (int r = 0; r < 4; r++) {
                    float vo = __shfl_xor(vv[r], 1, 64);   // DPP pair-swap
                    if (!(l15 & 1))
                        *(f16x2*)&sC[nb2][(16 * w + 4 * q + r) * PITCH + 16 * c2 + l15]
                            = pack_h2(vv[r], vo);
                }
            }
            // wave-local max: 4 DPP shfls + 4 readlanes (no LDS, no ds_permute)
            wmax = fmaxf(wmax, __shfl_xor(wmax, 1, 64));
            wmax = fmaxf(wmax, __shfl_xor(wmax, 2, 64));
            wmax = fmaxf(wmax, __shfl_xor(wmax, 4, 64));
            wmax = fmaxf(wmax, __shfl_xor(wmax, 8, 64));
            smax = fmaxf(fmaxf(bcastf(wmax, 0),  bcastf(wmax, 16)),
                         fmaxf(bcastf(wmax, 32), bcastf(wmax, 48)));
            cb ^= 1;
        }
    }

    // ---- store own row block TRANSPOSED: wsCt[col*64 + row] = C[row][col]
    {
        unsigned short tmp[16];
        #pragma unroll
        for (int r = 0; r < 16; r++)
            tmp[r] = __builtin_bit_cast(unsigned short, sC[cb][(16 * w + r) * PITCH + lane]);
        f16_t* dst = wsCt + ((size_t)(b * NCH + c)) * 4096 + lane * 64 + 16 * w;
        ((int4*)dst)[0] = *(const int4*)&tmp[0];
        ((int4*)dst)[1] = *(const int4*)&tmp[8];
        if (lane == 0) wsD[(b * NCH + c) * 4 + w] = D;
    }
}

// =====================================================================
// Kernel 2: one wave per batch, no LDS, no barriers. Lane j holds column j
// of each chunk matrix (C^T row j, contiguous 128 B) in registers, prefetched
// one chunk ahead. Dot accumulated in 4 groups by k-block (per-wave shifts
// D_w recombined exactly as 2^(D_w - Dmax)).
// =====================================================================
__global__ __launch_bounds__(64, 1)
void crf_combine(const float* __restrict__ feats, const int* __restrict__ mask,
                 const int* __restrict__ tags, const float* __restrict__ trans,
                 const f16_t* __restrict__ wsCt, const float* __restrict__ wsD,
                 float* __restrict__ out) {
    const int b    = blockIdx.x;
    const int lane = threadIdx.x;

    // ---------------- gold score ----------------
    float gsum = 0.f;
    int   lcnt = 0;
    for (int s = lane; s < NS; s += 64) {
        int   m  = mask[b * NS + s];
        int   tg = tags[b * NS + s];
        int   pv = (s == 0) ? START_TAG : tags[b * NS + s - 1];
        float e  = feats[((size_t)b * NS + s) * T + tg];
        float tr = trans[pv * T + tg];
        if (m) { gsum += e + tr; lcnt += 1; }
    }
    #pragma unroll
    for (int off = 32; off > 0; off >>= 1) {
        gsum += __shfl_down(gsum, off, 64);
        lcnt += __shfl_down(lcnt, off, 64);
    }
    float goldb = 0.f;
    if (lane == 0) goldb = gsum + trans[tags[b * NS + lcnt - 1] * T + STOP_TAG];

    // ---------------- part init (t = 0), log2 domain ----------------
    float part = (lane < T)
        ? (feats[(size_t)b * NS * T + lane] + trans[START_TAG * T + lane]) * LOG2E
        : NEG_BIG;

    // ---------------- per-(chunk,wave) shifts + chunk 0 matrix --------------
    float4 Dq[NCH];
    #pragma unroll
    for (int c = 0; c < NCH; c++) Dq[c] = ((const float4*)wsD)[b * NCH + c];

    int cur[32], nxt[32];
    {
        const f16_t* src = wsCt + (size_t)b * NCH * 4096 + lane * 64;
        #pragma unroll
        for (int kk = 0; kk < 8; kk++)
            *(int4*)&cur[4 * kk] = ((const int4*)src)[kk];
    }

    #pragma unroll
    for (int c = 0; c < NCH; c++) {
        if (c + 1 < NCH) {
            const f16_t* src = wsCt + (size_t)(b * NCH + c + 1) * 4096 + lane * 64;
            #pragma unroll
            for (int kk = 0; kk < 8; kk++)
                *(int4*)&nxt[4 * kk] = ((const int4*)src)[kk];
        }

        // true-max shift (ex must fit packed f16)
        float sft = part;
        #pragma unroll
        for (int off = 32; off > 0; off >>= 1) sft = fmaxf(sft, __shfl_xor(sft, off, 64));
        float ex  = fexp2(part - sft);
        float exo = __shfl_xor(ex, 1, 64);
        f16x2 pk  = pack_h2(ex, exo);     // even lane 2k holds (ex[2k], ex[2k+1])

        // 4 accumulators by k-block (rows [16u,16u+16) -> pairs [8u,8u+8))
        float a0 = 0.f, a1 = 0.f, a2 = 0.f, a3 = 0.f;
        #pragma unroll
        for (int p = 0; p < 8; p++)
            a0 = __builtin_amdgcn_fdot2(bcast_h2(pk, 2 * p), __builtin_bit_cast(f16x2, cur[p]), a0, false);
        #pragma unroll
        for (int p = 8; p < 16; p++)
            a1 = __builtin_amdgcn_fdot2(bcast_h2(pk, 2 * p), __builtin_bit_cast(f16x2, cur[p]), a1, false);
        #pragma unroll
        for (int p = 16; p < 24; p++)
            a2 = __builtin_amdgcn_fdot2(bcast_h2(pk, 2 * p), __builtin_bit_cast(f16x2, cur[p]), a2, false);
        a3 = __builtin_amdgcn_fdot2(bcast_h2(pk, 48), __builtin_bit_cast(f16x2, cur[24]), a3, false);

        const float4 Dv = Dq[c];
        float Dm = fmaxf(fmaxf(Dv.x, Dv.y), fmaxf(Dv.z, Dv.w));
        float SS = a0 * fexp2(Dv.x - Dm) + a1 * fexp2(Dv.y - Dm)
                 + a2 * fexp2(Dv.z - Dm) + a3 * fexp2(Dv.w - Dm);
        part = sft + Dm + flog2(SS);

        if (c + 1 < NCH) {
            #pragma unroll
            for (int kk = 0; kk < 32; kk++) cur[kk] = nxt[kk];
        }
    }

    // ---------------- terminal LSE to STOP + output ----------------
    float v = (lane < T) ? part + trans[lane * T + STOP_TAG] * LOG2E : NEG_BIG;
    float mx = v;
    #pragma unroll
    for (int off = 32; off > 0; off >>= 1) mx = fmaxf(mx, __shfl_xor(mx, off, 64));
    float ee = (lane < T) ? fexp2(v - mx) : 0.f;
    #pragma unroll
    for (int off = 32; off > 0; off >>= 1) ee += __shfl_xor(ee, off, 64);
    if (lane == 0) {
        float fwd = (mx + flog2(ee)) * LN2F;   // back to nats
        atomicAdd(out, fwd - goldb);
    }
}

extern "C" void kernel_launch(void* const* d_in, const int* in_sizes, int n_in,
                              void* d_out, int out_size, void* d_ws, size_t ws_size,
                              hipStream_t stream) {
    const float* feats = (const float*)d_in[0];
    const int*   mask  = (const int*)d_in[1];
    const int*   tags  = (const int*)d_in[2];
    const float* trans = (const float*)d_in[3];
    float* out = (float*)d_out;

    f16_t* wsCt = (f16_t*)d_ws;
    float* wsD  = (float*)((char*)d_ws + (size_t)NB * NCH * 4096 * sizeof(f16_t));

    crf_chunk<<<dim3(NCH, NB), 256, 0, stream>>>(feats, mask, trans, wsCt, wsD, out);
    crf_combine<<<NB, 64, 0, stream>>>(feats, mask, tags, trans, wsCt, wsD, out);
}